// Round 5
// baseline (880.436 us; speedup 1.0000x reference)
//
#include <hip/hip_runtime.h>

typedef unsigned short u16;
typedef __attribute__((ext_vector_type(8))) short short8;   // 8 bf16 = 4 VGPRs
typedef __attribute__((ext_vector_type(4))) float f32x4;

#define NQn 100000
#define NAn 200000
#define E1n 250000
#define E2n 250000
#define E3n 500000
#define NLn 100000
#define SLOTS 40   // max in-degree bucket capacity; Poisson(5) => P(>40) ~ 1e-22

__device__ __forceinline__ float bf2f(u16 u) {
    return __uint_as_float(((unsigned)u) << 16);
}
__device__ __forceinline__ u16 f2bf(float f) {
    unsigned x = __float_as_uint(f);
    unsigned r = (x + 0x7fffu + ((x >> 16) & 1u)) >> 16;
    return (u16)r;
}
__device__ __forceinline__ float sigmoidf_(float x) {
    return 1.f / (1.f + __expf(-x));
}

// -------- fold per-relation transforms into K/V weights (fp32 in, bf16 out) --------
// Wbig cols: [0,64): Wq ; [64,128): Wk@A(t0) ; [128,192): Wv@M(t0) ;
//            [192,256): Wk@A(t1) ; [256,320): Wv@M(t1)
// NOTE: v-section always sits +64 columns after its k-section (used by gather).
__global__ void fold_kernel(
    const float* __restrict__ Wk, const float* __restrict__ Wv, const float* __restrict__ Wq,
    const float* __restrict__ bk, const float* __restrict__ bv, const float* __restrict__ bq,
    const float* __restrict__ a_rel, const float* __restrict__ m_rel,
    int t0, int t1, u16* __restrict__ Wbig, float* __restrict__ bbig, int NOUT)
{
    const int total = 65 * NOUT;   // 64 weight rows + 1 bias row
    for (int idx = blockIdx.x * blockDim.x + threadIdx.x; idx < total;
         idx += gridDim.x * blockDim.x) {
        const int c   = idx / NOUT;
        const int col = idx - c * NOUT;
        const int grp = col >> 6;
        const int oc  = col & 63;
        const int h   = oc >> 5, e = oc & 31;
        if (c < 64) {
            float val;
            if (grp == 0) {
                val = Wq[c * 64 + oc];
            } else {
                const int t = (grp <= 2) ? t0 : t1;
                const float* W = (grp & 1) ? Wk : Wv;
                const float* T = (grp & 1) ? a_rel : m_rel;
                float s = 0.f;
                for (int d = 0; d < 32; ++d)
                    s = fmaf(W[c * 64 + h * 32 + d],
                             T[((t * 2 + h) * 32 + d) * 32 + e], s);
                val = s;
            }
            Wbig[c * NOUT + col] = f2bf(val);
        } else {
            float val;
            if (grp == 0) {
                val = bq[oc];
            } else {
                const int t = (grp <= 2) ? t0 : t1;
                const float* B = (grp & 1) ? bk : bv;
                const float* T = (grp & 1) ? a_rel : m_rel;
                float s = 0.f;
                for (int d = 0; d < 32; ++d)
                    s = fmaf(B[h * 32 + d],
                             T[((t * 2 + h) * 32 + d) * 32 + e], s);
                val = s;
            }
            bbig[col] = val;
        }
    }
}

// -------- MFMA fused node projection --------------------------------------
template <int NOUT>
__global__ __launch_bounds__(256, 2) void node_mfma(
    const float* __restrict__ x, int N,
    const float* __restrict__ Win, const float* __restrict__ bin,
    const u16* __restrict__ Wbig, const float* __restrict__ bbig,
    u16* __restrict__ h_out, u16* __restrict__ big_out)
{
    constexpr int NT = NOUT / 16;            // stage-2 col tiles
    __shared__ __align__(16) short sB1[4 * 4 * 64 * 8];   // [kt][nt][lane][j], 16 KB
    __shared__ __align__(16) short sB2[2 * NT * 64 * 8];  // [kt2][nt][lane][j]
    __shared__ __align__(16) short sH[4][16 * 72];        // per-wave h tile, stride 72
    __shared__ float sb1[64];
    __shared__ float sb2[NOUT];

    const int tid = threadIdx.x;
    for (int idx = tid; idx < 4 * 4 * 64 * 8; idx += 256) {
        const int j = idx & 7;
        const int ln = (idx >> 3) & 63;
        const int f = idx >> 9;              // kt*4 + nt
        const int kt = f >> 2, nt = f & 3;
        const int k = kt * 32 + (ln >> 4) * 8 + j;
        const int n = nt * 16 + (ln & 15);
        sB1[idx] = (short)f2bf(Win[k * 64 + n]);
    }
    for (int idx = tid; idx < 2 * NT * 64 * 8; idx += 256) {
        const int j = idx & 7;
        const int ln = (idx >> 3) & 63;
        const int f = idx >> 9;              // kt2*NT + nt
        const int kt2 = f / NT, nt = f - kt2 * NT;
        const int k = kt2 * 32 + (ln >> 4) * 8 + j;
        const int n = nt * 16 + (ln & 15);
        sB2[idx] = (short)Wbig[k * NOUT + n];
    }
    if (tid < 64) sb1[tid] = bin[tid];
    for (int i = tid; i < NOUT; i += 256) sb2[i] = bbig[i];
    __syncthreads();

    const int wave = tid >> 6;
    const int lane = tid & 63;
    const int quad = lane >> 4;
    const int mrow = lane & 15;
    short* const myH = &sH[wave][0];

    const int ntiles = (N + 63) >> 6;
    for (int tile = blockIdx.x; tile < ntiles; tile += gridDim.x) {
        const int nbase = tile * 64 + wave * 16;
        const int node = nbase + mrow;

        short8 a1[4];
        if (node < N) {
            const float* xp = x + (size_t)node * 128 + quad * 8;
            #pragma unroll
            for (int kt = 0; kt < 4; ++kt) {
                const float4 u0 = *(const float4*)(xp + kt * 32);
                const float4 u1 = *(const float4*)(xp + kt * 32 + 4);
                short8 f;
                f[0] = (short)f2bf(u0.x); f[1] = (short)f2bf(u0.y);
                f[2] = (short)f2bf(u0.z); f[3] = (short)f2bf(u0.w);
                f[4] = (short)f2bf(u1.x); f[5] = (short)f2bf(u1.y);
                f[6] = (short)f2bf(u1.z); f[7] = (short)f2bf(u1.w);
                a1[kt] = f;
            }
        } else {
            #pragma unroll
            for (int kt = 0; kt < 4; ++kt) a1[kt] = short8{0,0,0,0,0,0,0,0};
        }

        #pragma unroll
        for (int nt = 0; nt < 4; ++nt) {
            const float bv = sb1[nt * 16 + mrow];
            f32x4 acc = {bv, bv, bv, bv};
            #pragma unroll
            for (int kt = 0; kt < 4; ++kt) {
                const short8 bf = *(const short8*)&sB1[((kt * 4 + nt) * 64 + lane) * 8];
                acc = __builtin_amdgcn_mfma_f32_16x16x32_bf16(a1[kt], bf, acc, 0, 0, 0);
            }
            #pragma unroll
            for (int r = 0; r < 4; ++r) {
                const int row = quad * 4 + r;
                const int nd = nbase + row;
                const u16 hb = f2bf(fmaxf(acc[r], 0.f));
                myH[row * 72 + nt * 16 + mrow] = (short)hb;
                if (nd < N) h_out[(size_t)nd * 64 + nt * 16 + mrow] = hb;
            }
        }

        short8 a2[2];
        #pragma unroll
        for (int kt2 = 0; kt2 < 2; ++kt2)
            a2[kt2] = *(const short8*)&myH[mrow * 72 + kt2 * 32 + quad * 8];

        for (int nt = 0; nt < NT; ++nt) {
            const float bv = sb2[nt * 16 + mrow];
            f32x4 acc = {bv, bv, bv, bv};
            const short8 b0 = *(const short8*)&sB2[((0 * NT + nt) * 64 + lane) * 8];
            acc = __builtin_amdgcn_mfma_f32_16x16x32_bf16(a2[0], b0, acc, 0, 0, 0);
            const short8 b1 = *(const short8*)&sB2[((1 * NT + nt) * 64 + lane) * 8];
            acc = __builtin_amdgcn_mfma_f32_16x16x32_bf16(a2[1], b1, acc, 0, 0, 0);
            #pragma unroll
            for (int r = 0; r < 4; ++r) {
                const int nd = nbase + quad * 4 + r;
                if (nd < N)
                    big_out[(size_t)nd * NOUT + nt * 16 + mrow] = f2bf(acc[r]);
            }
        }
    }
}

// -------- scatter: bucket edges by destination (no score computation) ------
// payload.x = (src*srcStride + kBase) | relBit   (k-offset, mult of 32; v = +64)
// payload.y = bits of per-edge weight w
__global__ __launch_bounds__(256) void scatter_kernel(
    const int* __restrict__ src, const int* __restrict__ dst, int E,
    int srcStride, int kBase, int relBit, const float* __restrict__ w,
    int* __restrict__ cursor, int2* __restrict__ payload)
{
    const int e = blockIdx.x * 256 + threadIdx.x;
    if (e >= E) return;
    const int s = src[e];
    const int d = dst[e];
    if ((unsigned)d >= (unsigned)NQn) return;   // guaranteed not to happen; memory safety
    const int slot = atomicAdd(&cursor[d], 1);
    if (slot < SLOTS)
        payload[(size_t)d * SLOTS + slot] =
            make_int2((s * srcStride + kBase) | relBit, __float_as_int(w[e]));
}

// -------- gather + softmax + gelu + Wo + skip, fused (wave per dst node) ---
// Inner loop batched by 8: all 16 loads (8 k-rows + 8 v-rows) issued before
// the first reduction -> ~16 outstanding 128B loads/wave (MLP fix, r4).
__global__ __launch_bounds__(256) void gather_finalize(
    const int* __restrict__ cursor, const int2* __restrict__ payload,
    const u16* __restrict__ srcArr,
    const u16* __restrict__ qArr, int qStride,
    const float* __restrict__ p_rel, int t0, int t1,
    const u16* __restrict__ h_in,
    const float* __restrict__ Wo, const float* __restrict__ bo,
    const float* __restrict__ skip, u16* __restrict__ z_out, int N)
{
    __shared__ float sWo[64 * 64];
    __shared__ float sbo[64];
    for (int i = threadIdx.x; i < 4096; i += 256) sWo[i] = Wo[i];
    if (threadIdx.x < 64) sbo[threadIdx.x] = bo[threadIdx.x];
    __syncthreads();

    const float sk = sigmoidf_(skip[0]);
    const int wv = threadIdx.x >> 6, lane = threadIdx.x & 63, h = lane >> 5;
    const float isq = 0.17677669529663687f;   // 1/sqrt(32)
    const float s0 = p_rel[t0 * 2 + h] * isq;
    const float s1 = p_rel[t1 * 2 + h] * isq;
    const int ntiles = (N + 3) >> 2;

    for (int tile = blockIdx.x; tile < ntiles; tile += gridDim.x) {
        const int node = tile * 4 + wv;
        if (node >= N) continue;               // no barriers below: safe
        int cnt = (node < NQn) ? cursor[node] : 0;
        if (cnt > SLOTS) cnt = SLOTS;
        const float qv = bf2f(qArr[(size_t)node * qStride + lane]);

        // preload up to SLOTS<=64 payloads, one per lane; broadcast via shfl
        int myx = 0, myy = 0;
        if (lane < cnt) {
            const int2 e = payload[(size_t)node * SLOTS + lane];
            myx = e.x; myy = e.y;
        }

        float acc = 0.f, den = 0.f;
        for (int base = 0; base < cnt; base += 8) {
            const int nb = cnt - base;          // >=1; use min(nb,8) lanes of work
            int ex_[8]; float w_[8];
            #pragma unroll
            for (int i = 0; i < 8; ++i) {
                ex_[i] = __shfl(myx, base + i);
                w_[i]  = __int_as_float(__shfl(myy, base + i));
            }
            float kv_[8], vv_[8];
            #pragma unroll
            for (int i = 0; i < 8; ++i) {
                if (i < nb) {
                    const int ko = ex_[i] & ~31;
                    kv_[i] = bf2f(srcArr[(size_t)ko + lane]);
                    vv_[i] = bf2f(srcArr[(size_t)ko + 64 + lane]);
                }
            }
            #pragma unroll
            for (int i = 0; i < 8; ++i) {
                if (i < nb) {
                    float p = qv * kv_[i];
                    p += __shfl_xor(p, 16);
                    p += __shfl_xor(p, 8);
                    p += __shfl_xor(p, 4);
                    p += __shfl_xor(p, 2);
                    p += __shfl_xor(p, 1);
                    const float sc = (ex_[i] & 1) ? s1 : s0;
                    const float exv = __expf(p * sc);
                    acc = fmaf(exv * w_[i], vv_[i], acc);
                    den += exv;
                }
            }
        }

        const float xx = acc / (den + 1e-16f);
        const float u = 0.7978845608028654f * (xx + 0.044715f * xx * xx * xx);
        const float th = 1.f - 2.f / (__expf(2.f * u) + 1.f);
        const float g = 0.5f * xx * (1.f + th);

        // out[lane] = bo[lane] + sum_c g_c * Wo[c][lane]  (g_c via readlane)
        float o = sbo[lane];
        #pragma unroll 8
        for (int c = 0; c < 64; ++c)
            o = fmaf(__shfl(g, c), sWo[c * 64 + lane], o);
        const float hv = bf2f(h_in[(size_t)node * 64 + lane]);
        z_out[(size_t)node * 64 + lane] = f2bf(sk * o + (1.f - sk) * hv);
    }
}

// -------- decoder: sigmoid(dot64) link prediction --------------------------
__global__ __launch_bounds__(256) void decoder_kernel(
    const u16* __restrict__ z_q, const u16* __restrict__ z_a,
    const int* __restrict__ pos_idx, const int* __restrict__ neg_idx,
    float* __restrict__ out)
{
    const int gid = blockIdx.x * 256 + threadIdx.x;
    const int o = gid >> 5;         // half-wave per output
    if (o >= 2 * NLn) return;
    const int lane = threadIdx.x & 31;
    const int* idx;
    int i;
    if (o < NLn) { idx = pos_idx; i = o; }
    else         { idx = neg_idx; i = o - NLn; }
    const int r0 = idx[i];
    const int r1 = idx[NLn + i];
    float s = bf2f(z_q[(size_t)r0 * 64 + 2 * lane])     * bf2f(z_a[(size_t)r1 * 64 + 2 * lane])
            + bf2f(z_q[(size_t)r0 * 64 + 2 * lane + 1]) * bf2f(z_a[(size_t)r1 * 64 + 2 * lane + 1]);
    s += __shfl_xor(s, 16);
    s += __shfl_xor(s, 8);
    s += __shfl_xor(s, 4);
    s += __shfl_xor(s, 2);
    s += __shfl_xor(s, 1);
    if (lane == 0) out[o] = sigmoidf_(s);
}

extern "C" void kernel_launch(void* const* d_in, const int* in_sizes, int n_in,
                              void* d_out, int out_size, void* d_ws, size_t ws_size,
                              hipStream_t stream)
{
    (void)in_sizes; (void)n_in; (void)out_size;
    const float* x_q   = (const float*)d_in[0];
    const float* x_a   = (const float*)d_in[1];
    const int* ei_qca  = (const int*)d_in[2];
    const int* ei_qwa  = (const int*)d_in[3];
    const int* ei_rev  = (const int*)d_in[4];
    const int* pos_idx = (const int*)d_in[5];
    const int* neg_idx = (const int*)d_in[6];
    const float* w_qca = (const float*)d_in[7];
    const float* w_qwa = (const float*)d_in[8];
    const float* w_rev = (const float*)d_in[9];
    const float* W_in_q = (const float*)d_in[10]; const float* b_in_q = (const float*)d_in[11];
    const float* W_in_a = (const float*)d_in[12]; const float* b_in_a = (const float*)d_in[13];
    const float* Wk_qn = (const float*)d_in[14], *bk_qn = (const float*)d_in[15];
    const float* Wq_qn = (const float*)d_in[16], *bq_qn = (const float*)d_in[17];
    const float* Wv_qn = (const float*)d_in[18], *bv_qn = (const float*)d_in[19];
    const float* Wk_an = (const float*)d_in[20], *bk_an = (const float*)d_in[21];
    const float* Wq_an = (const float*)d_in[22], *bq_an = (const float*)d_in[23];
    const float* Wv_an = (const float*)d_in[24], *bv_an = (const float*)d_in[25];
    const float* a_rel = (const float*)d_in[26];
    const float* m_rel = (const float*)d_in[27];
    const float* p_rel = (const float*)d_in[28];
    const float* Wo_qn = (const float*)d_in[29], *bo_qn = (const float*)d_in[30];
    const float* Wo_an = (const float*)d_in[31], *bo_an = (const float*)d_in[32];
    const float* skip_qn = (const float*)d_in[33], *skip_an = (const float*)d_in[34];

    char* ws = (char*)d_ws;
    size_t off = 0;
    auto alloc = [&](size_t bytes) -> char* {
        char* p = ws + off;
        off = (off + bytes + 255) & ~(size_t)255;
        return p;
    };
    u16* big_q = (u16*)alloc((size_t)NQn * 320 * 2);  // q | k0 | v0 | k1 | v1
    u16* big_a = (u16*)alloc((size_t)NAn * 192 * 2);  // q | k2 | v2
    u16* h_q   = (u16*)alloc((size_t)NQn * 64 * 2);
    u16* h_a   = (u16*)alloc((size_t)NAn * 64 * 2);
    u16* z_q   = (u16*)alloc((size_t)NQn * 64 * 2);
    u16* z_a   = (u16*)alloc((size_t)NAn * 64 * 2);
    int2* payload_a = (int2*)alloc((size_t)NQn * SLOTS * 8);  // dst of E1/E2 < NQn
    int2* payload_q = (int2*)alloc((size_t)NQn * SLOTS * 8);
    char* zero_start = ws + off;
    int* cursor_a = (int*)alloc((size_t)NQn * 4);
    int* cursor_q = (int*)alloc((size_t)NQn * 4);
    char* zero_end = ws + off;
    u16* Wbig_q = (u16*)alloc(64 * 320 * 2);
    float* bbig_q = (float*)alloc(320 * 4);
    u16* Wbig_a = (u16*)alloc(64 * 192 * 2);
    float* bbig_a = (float*)alloc(192 * 4);

    if (off > ws_size) return;  // workspace too small: leave output zeroed (visible failure)

    hipMemsetAsync(zero_start, 0, (size_t)(zero_end - zero_start), stream);

    fold_kernel<<<64, 256, 0, stream>>>(Wk_qn, Wv_qn, Wq_qn, bk_qn, bv_qn, bq_qn,
                                        a_rel, m_rel, 0, 1, Wbig_q, bbig_q, 320);
    fold_kernel<<<64, 256, 0, stream>>>(Wk_an, Wv_an, Wq_an, bk_an, bv_an, bq_an,
                                        a_rel, m_rel, 2, -1, Wbig_a, bbig_a, 192);

    node_mfma<320><<<512, 256, 0, stream>>>(x_q, NQn, W_in_q, b_in_q, Wbig_q, bbig_q, h_q, big_q);
    node_mfma<192><<<512, 256, 0, stream>>>(x_a, NAn, W_in_a, b_in_a, Wbig_a, bbig_a, h_a, big_a);

    scatter_kernel<<<(E1n + 255) / 256, 256, 0, stream>>>(
        ei_qca, ei_qca + E1n, E1n, 320, 64, 0, w_qca, cursor_a, payload_a);
    scatter_kernel<<<(E2n + 255) / 256, 256, 0, stream>>>(
        ei_qwa, ei_qwa + E2n, E2n, 320, 192, 1, w_qwa, cursor_a, payload_a);
    scatter_kernel<<<(E3n + 255) / 256, 256, 0, stream>>>(
        ei_rev, ei_rev + E3n, E3n, 192, 64, 0, w_rev, cursor_q, payload_q);

    // answer-node aggregation: edges from q-nodes (big_q), q rows in big_a
    gather_finalize<<<2048, 256, 0, stream>>>(
        cursor_a, payload_a, big_q, big_a, 192, p_rel, 0, 1,
        h_a, Wo_an, bo_an, skip_an, z_a, NAn);
    // question-node aggregation: edges from a-nodes (big_a), q rows in big_q
    gather_finalize<<<2048, 256, 0, stream>>>(
        cursor_q, payload_q, big_a, big_q, 320, p_rel, 2, 2,
        h_q, Wo_qn, bo_qn, skip_qn, z_q, NQn);

    decoder_kernel<<<(2 * NLn * 32 + 255) / 256, 256, 0, stream>>>(
        z_q, z_a, pos_idx, neg_idx, (float*)d_out);
}

// Round 6
// 746.642 us; speedup vs baseline: 1.1792x; 1.1792x over previous
//
#include <hip/hip_runtime.h>

typedef unsigned short u16;
typedef __attribute__((ext_vector_type(8))) short short8;   // 8 bf16 = 4 VGPRs
typedef __attribute__((ext_vector_type(4))) float f32x4;

#define NQn 100000
#define NAn 200000
#define E1n 250000
#define E2n 250000
#define E3n 500000
#define NLn 100000
#define SLOTS 40   // max in-degree bucket capacity; Poisson(5) => P(>40) ~ 1e-22

__device__ __forceinline__ float bf2f(u16 u) {
    return __uint_as_float(((unsigned)u) << 16);
}
__device__ __forceinline__ u16 f2bf(float f) {
    unsigned x = __float_as_uint(f);
    unsigned r = (x + 0x7fffu + ((x >> 16) & 1u)) >> 16;
    return (u16)r;
}
__device__ __forceinline__ float sigmoidf_(float x) {
    return 1.f / (1.f + __expf(-x));
}

// -------- fold per-relation transforms into K/V weights (fp32 in, bf16 out) --------
// Wbig cols: [0,64): Wq ; [64,128): Wk@A(t0) ; [128,192): Wv@M(t0) ;
//            [192,256): Wk@A(t1) ; [256,320): Wv@M(t1)
__global__ void fold_kernel(
    const float* __restrict__ Wk, const float* __restrict__ Wv, const float* __restrict__ Wq,
    const float* __restrict__ bk, const float* __restrict__ bv, const float* __restrict__ bq,
    const float* __restrict__ a_rel, const float* __restrict__ m_rel,
    int t0, int t1, u16* __restrict__ Wbig, float* __restrict__ bbig, int NOUT)
{
    const int total = 65 * NOUT;   // 64 weight rows + 1 bias row
    for (int idx = blockIdx.x * blockDim.x + threadIdx.x; idx < total;
         idx += gridDim.x * blockDim.x) {
        const int c   = idx / NOUT;
        const int col = idx - c * NOUT;
        const int grp = col >> 6;
        const int oc  = col & 63;
        const int h   = oc >> 5, e = oc & 31;
        if (c < 64) {
            float val;
            if (grp == 0) {
                val = Wq[c * 64 + oc];
            } else {
                const int t = (grp <= 2) ? t0 : t1;
                const float* W = (grp & 1) ? Wk : Wv;
                const float* T = (grp & 1) ? a_rel : m_rel;
                float s = 0.f;
                for (int d = 0; d < 32; ++d)
                    s = fmaf(W[c * 64 + h * 32 + d],
                             T[((t * 2 + h) * 32 + d) * 32 + e], s);
                val = s;
            }
            Wbig[c * NOUT + col] = f2bf(val);
        } else {
            float val;
            if (grp == 0) {
                val = bq[oc];
            } else {
                const int t = (grp <= 2) ? t0 : t1;
                const float* B = (grp & 1) ? bk : bv;
                const float* T = (grp & 1) ? a_rel : m_rel;
                float s = 0.f;
                for (int d = 0; d < 32; ++d)
                    s = fmaf(B[h * 32 + d],
                             T[((t * 2 + h) * 32 + d) * 32 + e], s);
                val = s;
            }
            bbig[col] = val;
        }
    }
}

// -------- MFMA fused node projection --------------------------------------
template <int NOUT>
__global__ __launch_bounds__(256, 2) void node_mfma(
    const float* __restrict__ x, int N,
    const float* __restrict__ Win, const float* __restrict__ bin,
    const u16* __restrict__ Wbig, const float* __restrict__ bbig,
    u16* __restrict__ h_out, u16* __restrict__ big_out)
{
    constexpr int NT = NOUT / 16;            // stage-2 col tiles
    __shared__ __align__(16) short sB1[4 * 4 * 64 * 8];   // [kt][nt][lane][j], 16 KB
    __shared__ __align__(16) short sB2[2 * NT * 64 * 8];  // [kt2][nt][lane][j]
    __shared__ __align__(16) short sH[4][16 * 72];        // per-wave h tile, stride 72
    __shared__ float sb1[64];
    __shared__ float sb2[NOUT];

    const int tid = threadIdx.x;
    for (int idx = tid; idx < 4 * 4 * 64 * 8; idx += 256) {
        const int j = idx & 7;
        const int ln = (idx >> 3) & 63;
        const int f = idx >> 9;              // kt*4 + nt
        const int kt = f >> 2, nt = f & 3;
        const int k = kt * 32 + (ln >> 4) * 8 + j;
        const int n = nt * 16 + (ln & 15);
        sB1[idx] = (short)f2bf(Win[k * 64 + n]);
    }
    for (int idx = tid; idx < 2 * NT * 64 * 8; idx += 256) {
        const int j = idx & 7;
        const int ln = (idx >> 3) & 63;
        const int f = idx >> 9;              // kt2*NT + nt
        const int kt2 = f / NT, nt = f - kt2 * NT;
        const int k = kt2 * 32 + (ln >> 4) * 8 + j;
        const int n = nt * 16 + (ln & 15);
        sB2[idx] = (short)Wbig[k * NOUT + n];
    }
    if (tid < 64) sb1[tid] = bin[tid];
    for (int i = tid; i < NOUT; i += 256) sb2[i] = bbig[i];
    __syncthreads();

    const int wave = tid >> 6;
    const int lane = tid & 63;
    const int quad = lane >> 4;
    const int mrow = lane & 15;
    short* const myH = &sH[wave][0];

    const int ntiles = (N + 63) >> 6;
    for (int tile = blockIdx.x; tile < ntiles; tile += gridDim.x) {
        const int nbase = tile * 64 + wave * 16;
        const int node = nbase + mrow;

        short8 a1[4];
        if (node < N) {
            const float* xp = x + (size_t)node * 128 + quad * 8;
            #pragma unroll
            for (int kt = 0; kt < 4; ++kt) {
                const float4 u0 = *(const float4*)(xp + kt * 32);
                const float4 u1 = *(const float4*)(xp + kt * 32 + 4);
                short8 f;
                f[0] = (short)f2bf(u0.x); f[1] = (short)f2bf(u0.y);
                f[2] = (short)f2bf(u0.z); f[3] = (short)f2bf(u0.w);
                f[4] = (short)f2bf(u1.x); f[5] = (short)f2bf(u1.y);
                f[6] = (short)f2bf(u1.z); f[7] = (short)f2bf(u1.w);
                a1[kt] = f;
            }
        } else {
            #pragma unroll
            for (int kt = 0; kt < 4; ++kt) a1[kt] = short8{0,0,0,0,0,0,0,0};
        }

        #pragma unroll
        for (int nt = 0; nt < 4; ++nt) {
            const float bv = sb1[nt * 16 + mrow];
            f32x4 acc = {bv, bv, bv, bv};
            #pragma unroll
            for (int kt = 0; kt < 4; ++kt) {
                const short8 bf = *(const short8*)&sB1[((kt * 4 + nt) * 64 + lane) * 8];
                acc = __builtin_amdgcn_mfma_f32_16x16x32_bf16(a1[kt], bf, acc, 0, 0, 0);
            }
            #pragma unroll
            for (int r = 0; r < 4; ++r) {
                const int row = quad * 4 + r;
                const int nd = nbase + row;
                const u16 hb = f2bf(fmaxf(acc[r], 0.f));
                myH[row * 72 + nt * 16 + mrow] = (short)hb;
                if (nd < N) h_out[(size_t)nd * 64 + nt * 16 + mrow] = hb;
            }
        }

        short8 a2[2];
        #pragma unroll
        for (int kt2 = 0; kt2 < 2; ++kt2)
            a2[kt2] = *(const short8*)&myH[mrow * 72 + kt2 * 32 + quad * 8];

        for (int nt = 0; nt < NT; ++nt) {
            const float bv = sb2[nt * 16 + mrow];
            f32x4 acc = {bv, bv, bv, bv};
            const short8 b0 = *(const short8*)&sB2[((0 * NT + nt) * 64 + lane) * 8];
            acc = __builtin_amdgcn_mfma_f32_16x16x32_bf16(a2[0], b0, acc, 0, 0, 0);
            const short8 b1 = *(const short8*)&sB2[((1 * NT + nt) * 64 + lane) * 8];
            acc = __builtin_amdgcn_mfma_f32_16x16x32_bf16(a2[1], b1, acc, 0, 0, 0);
            #pragma unroll
            for (int r = 0; r < 4; ++r) {
                const int nd = nbase + quad * 4 + r;
                if (nd < N)
                    big_out[(size_t)nd * NOUT + nt * 16 + mrow] = f2bf(acc[r]);
            }
        }
    }
}

// -------- scatter: bucket edges by destination (no score computation) ------
// payload.x = (src*srcStride + kBase) | relBit   (k-offset, mult of 32; v = +64)
// payload.y = bits of per-edge weight w
__global__ __launch_bounds__(256) void scatter_kernel(
    const int* __restrict__ src, const int* __restrict__ dst, int E,
    int srcStride, int kBase, int relBit, const float* __restrict__ w,
    int* __restrict__ cursor, int2* __restrict__ payload)
{
    const int e = blockIdx.x * 256 + threadIdx.x;
    if (e >= E) return;
    const int s = src[e];
    const int d = dst[e];
    if ((unsigned)d >= (unsigned)NQn) return;   // guaranteed not to happen; memory safety
    const int slot = atomicAdd(&cursor[d], 1);
    if (slot < SLOTS)
        payload[(size_t)d * SLOTS + slot] =
            make_int2((s * srcStride + kBase) | relBit, __float_as_int(w[e]));
}

// -------- gather + softmax + gelu + MFMA-Wo + skip (wave per node) ---------
// r5 lesson: __shfl == ds_bpermute/ds_swizzle on the LDS pipe. The old
// 64-shfl Wo loop was ~740 LDS-pipe cyc/node == the whole kernel. Wo now
// done by MFMA: g,h rows -> wave-private LDS tile (1 ds_write each/node),
// A-frags 2x ds_read_b128 per 16 nodes, Wo B-frags resident in VGPRs.
__global__ __launch_bounds__(256) void gather_finalize(
    const int* __restrict__ cursor, const int2* __restrict__ payload,
    const u16* __restrict__ srcArr,
    const u16* __restrict__ qArr, int qStride,
    const float* __restrict__ p_rel, int t0, int t1,
    const u16* __restrict__ h_in,
    const float* __restrict__ Wo, const float* __restrict__ bo,
    const float* __restrict__ skip, u16* __restrict__ z_out, int N)
{
    __shared__ __align__(16) short sWoF[8 * 64 * 8];   // [kt*4+nt][lane][j] bf16 frags, 8 KB
    __shared__ __align__(16) short sG[4][16 * 72];     // per-wave gelu rows (bf16)
    __shared__ __align__(16) short sHh[4][16 * 72];    // per-wave h rows (raw bf16)
    __shared__ float sbo[64];

    const int tid = threadIdx.x;
    for (int idx = tid; idx < 8 * 64 * 8; idx += 256) {
        const int j = idx & 7;
        const int ln = (idx >> 3) & 63;
        const int f = idx >> 9;              // kt*4 + nt
        const int kt = f >> 2, nt = f & 3;
        const int k = kt * 32 + (ln >> 4) * 8 + j;
        const int n = nt * 16 + (ln & 15);
        sWoF[idx] = (short)f2bf(Wo[k * 64 + n]);
    }
    if (tid < 64) sbo[tid] = bo[tid];
    __syncthreads();

    const int wave = tid >> 6, lane = tid & 63;
    const int quad = lane >> 4, mrow = lane & 15;
    const int h = lane >> 5;

    // Wo B-fragments resident in VGPRs (8 x short8 = 32 VGPRs)
    short8 bw[8];
    #pragma unroll
    for (int f = 0; f < 8; ++f)
        bw[f] = *(const short8*)&sWoF[(f * 64 + lane) * 8];

    const float sk = sigmoidf_(skip[0]);
    const float isq = 0.17677669529663687f;   // 1/sqrt(32)
    const float s0 = p_rel[t0 * 2 + h] * isq;
    const float s1 = p_rel[t1 * 2 + h] * isq;

    short* const myG = &sG[wave][0];
    short* const myHh = &sHh[wave][0];

    const int ntiles = (N + 63) >> 6;
    for (int tile = blockIdx.x; tile < ntiles; tile += gridDim.x) {
        const int nbase = tile * 64 + wave * 16;

        for (int nl = 0; nl < 16; ++nl) {
            const int node = nbase + nl;
            float g = 0.f;
            u16 hraw = 0;
            if (node < N) {
                int cnt = (node < NQn) ? cursor[node] : 0;
                if (cnt > SLOTS) cnt = SLOTS;
                const float qv = bf2f(qArr[(size_t)node * qStride + lane]);
                hraw = h_in[(size_t)node * 64 + lane];

                int myx = 0, myy = 0;
                if (lane < cnt) {
                    const int2 e = payload[(size_t)node * SLOTS + lane];
                    myx = e.x; myy = e.y;
                }

                float acc = 0.f, den = 0.f;
                for (int i = 0; i < cnt; ++i) {
                    const int ex_ = __shfl(myx, i);
                    const int wb  = __shfl(myy, i);
                    const int koff = ex_ & ~31;
                    const float kv = bf2f(srcArr[(size_t)koff + lane]);
                    const float vv = bf2f(srcArr[(size_t)koff + 64 + lane]);
                    float p = qv * kv;
                    p += __shfl_xor(p, 16);
                    p += __shfl_xor(p, 8);
                    p += __shfl_xor(p, 4);
                    p += __shfl_xor(p, 2);
                    p += __shfl_xor(p, 1);
                    const float sc = (ex_ & 1) ? s1 : s0;
                    const float exv = __expf(p * sc);
                    acc = fmaf(exv * __int_as_float(wb), vv, acc);
                    den += exv;
                }

                const float xx = acc / (den + 1e-16f);
                const float u = 0.7978845608028654f * (xx + 0.044715f * xx * xx * xx);
                const float th = 1.f - 2.f / (__expf(2.f * u) + 1.f);
                g = 0.5f * xx * (1.f + th);
            }
            myG[nl * 72 + lane] = (short)f2bf(g);
            myHh[nl * 72 + lane] = (short)hraw;
        }

        // wave-private MFMA: Z16x64 = G16x64 @ Wo64x64 (+bo), then skip blend
        short8 ag[2];
        #pragma unroll
        for (int kt = 0; kt < 2; ++kt)
            ag[kt] = *(const short8*)&myG[mrow * 72 + kt * 32 + quad * 8];

        #pragma unroll
        for (int nt = 0; nt < 4; ++nt) {
            const float bov = sbo[nt * 16 + mrow];
            f32x4 acc = {bov, bov, bov, bov};
            acc = __builtin_amdgcn_mfma_f32_16x16x32_bf16(ag[0], bw[nt], acc, 0, 0, 0);
            acc = __builtin_amdgcn_mfma_f32_16x16x32_bf16(ag[1], bw[4 + nt], acc, 0, 0, 0);
            #pragma unroll
            for (int r = 0; r < 4; ++r) {
                const int row = quad * 4 + r;
                const int node = nbase + row;
                if (node < N) {
                    const float hv = bf2f((u16)myHh[row * 72 + nt * 16 + mrow]);
                    z_out[(size_t)node * 64 + nt * 16 + mrow] =
                        f2bf(sk * acc[r] + (1.f - sk) * hv);
                }
            }
        }
    }
}

// -------- decoder: sigmoid(dot64) link prediction --------------------------
__global__ __launch_bounds__(256) void decoder_kernel(
    const u16* __restrict__ z_q, const u16* __restrict__ z_a,
    const int* __restrict__ pos_idx, const int* __restrict__ neg_idx,
    float* __restrict__ out)
{
    const int gid = blockIdx.x * 256 + threadIdx.x;
    const int o = gid >> 5;         // half-wave per output
    if (o >= 2 * NLn) return;
    const int lane = threadIdx.x & 31;
    const int* idx;
    int i;
    if (o < NLn) { idx = pos_idx; i = o; }
    else         { idx = neg_idx; i = o - NLn; }
    const int r0 = idx[i];
    const int r1 = idx[NLn + i];
    float s = bf2f(z_q[(size_t)r0 * 64 + 2 * lane])     * bf2f(z_a[(size_t)r1 * 64 + 2 * lane])
            + bf2f(z_q[(size_t)r0 * 64 + 2 * lane + 1]) * bf2f(z_a[(size_t)r1 * 64 + 2 * lane + 1]);
    s += __shfl_xor(s, 16);
    s += __shfl_xor(s, 8);
    s += __shfl_xor(s, 4);
    s += __shfl_xor(s, 2);
    s += __shfl_xor(s, 1);
    if (lane == 0) out[o] = sigmoidf_(s);
}

extern "C" void kernel_launch(void* const* d_in, const int* in_sizes, int n_in,
                              void* d_out, int out_size, void* d_ws, size_t ws_size,
                              hipStream_t stream)
{
    (void)in_sizes; (void)n_in; (void)out_size;
    const float* x_q   = (const float*)d_in[0];
    const float* x_a   = (const float*)d_in[1];
    const int* ei_qca  = (const int*)d_in[2];
    const int* ei_qwa  = (const int*)d_in[3];
    const int* ei_rev  = (const int*)d_in[4];
    const int* pos_idx = (const int*)d_in[5];
    const int* neg_idx = (const int*)d_in[6];
    const float* w_qca = (const float*)d_in[7];
    const float* w_qwa = (const float*)d_in[8];
    const float* w_rev = (const float*)d_in[9];
    const float* W_in_q = (const float*)d_in[10]; const float* b_in_q = (const float*)d_in[11];
    const float* W_in_a = (const float*)d_in[12]; const float* b_in_a = (const float*)d_in[13];
    const float* Wk_qn = (const float*)d_in[14], *bk_qn = (const float*)d_in[15];
    const float* Wq_qn = (const float*)d_in[16], *bq_qn = (const float*)d_in[17];
    const float* Wv_qn = (const float*)d_in[18], *bv_qn = (const float*)d_in[19];
    const float* Wk_an = (const float*)d_in[20], *bk_an = (const float*)d_in[21];
    const float* Wq_an = (const float*)d_in[22], *bq_an = (const float*)d_in[23];
    const float* Wv_an = (const float*)d_in[24], *bv_an = (const float*)d_in[25];
    const float* a_rel = (const float*)d_in[26];
    const float* m_rel = (const float*)d_in[27];
    const float* p_rel = (const float*)d_in[28];
    const float* Wo_qn = (const float*)d_in[29], *bo_qn = (const float*)d_in[30];
    const float* Wo_an = (const float*)d_in[31], *bo_an = (const float*)d_in[32];
    const float* skip_qn = (const float*)d_in[33], *skip_an = (const float*)d_in[34];

    char* ws = (char*)d_ws;
    size_t off = 0;
    auto alloc = [&](size_t bytes) -> char* {
        char* p = ws + off;
        off = (off + bytes + 255) & ~(size_t)255;
        return p;
    };
    u16* big_q = (u16*)alloc((size_t)NQn * 320 * 2);  // q | k0 | v0 | k1 | v1
    u16* big_a = (u16*)alloc((size_t)NAn * 192 * 2);  // q | k2 | v2
    u16* h_q   = (u16*)alloc((size_t)NQn * 64 * 2);
    u16* h_a   = (u16*)alloc((size_t)NAn * 64 * 2);
    u16* z_q   = (u16*)alloc((size_t)NQn * 64 * 2);
    u16* z_a   = (u16*)alloc((size_t)NAn * 64 * 2);
    int2* payload_a = (int2*)alloc((size_t)NQn * SLOTS * 8);  // dst of E1/E2 < NQn
    int2* payload_q = (int2*)alloc((size_t)NQn * SLOTS * 8);
    char* zero_start = ws + off;
    int* cursor_a = (int*)alloc((size_t)NQn * 4);
    int* cursor_q = (int*)alloc((size_t)NQn * 4);
    char* zero_end = ws + off;
    u16* Wbig_q = (u16*)alloc(64 * 320 * 2);
    float* bbig_q = (float*)alloc(320 * 4);
    u16* Wbig_a = (u16*)alloc(64 * 192 * 2);
    float* bbig_a = (float*)alloc(192 * 4);

    if (off > ws_size) return;  // workspace too small: leave output zeroed (visible failure)

    hipMemsetAsync(zero_start, 0, (size_t)(zero_end - zero_start), stream);

    fold_kernel<<<64, 256, 0, stream>>>(Wk_qn, Wv_qn, Wq_qn, bk_qn, bv_qn, bq_qn,
                                        a_rel, m_rel, 0, 1, Wbig_q, bbig_q, 320);
    fold_kernel<<<64, 256, 0, stream>>>(Wk_an, Wv_an, Wq_an, bk_an, bv_an, bq_an,
                                        a_rel, m_rel, 2, -1, Wbig_a, bbig_a, 192);

    node_mfma<320><<<512, 256, 0, stream>>>(x_q, NQn, W_in_q, b_in_q, Wbig_q, bbig_q, h_q, big_q);
    node_mfma<192><<<512, 256, 0, stream>>>(x_a, NAn, W_in_a, b_in_a, Wbig_a, bbig_a, h_a, big_a);

    scatter_kernel<<<(E1n + 255) / 256, 256, 0, stream>>>(
        ei_qca, ei_qca + E1n, E1n, 320, 64, 0, w_qca, cursor_a, payload_a);
    scatter_kernel<<<(E2n + 255) / 256, 256, 0, stream>>>(
        ei_qwa, ei_qwa + E2n, E2n, 320, 192, 1, w_qwa, cursor_a, payload_a);
    scatter_kernel<<<(E3n + 255) / 256, 256, 0, stream>>>(
        ei_rev, ei_rev + E3n, E3n, 192, 64, 0, w_rev, cursor_q, payload_q);

    // answer-node aggregation: edges from q-nodes (big_q), q rows in big_a
    gather_finalize<<<2048, 256, 0, stream>>>(
        cursor_a, payload_a, big_q, big_a, 192, p_rel, 0, 1,
        h_a, Wo_an, bo_an, skip_an, z_a, NAn);
    // question-node aggregation: edges from a-nodes (big_a), q rows in big_q
    gather_finalize<<<2048, 256, 0, stream>>>(
        cursor_q, payload_q, big_a, big_q, 320, p_rel, 2, 2,
        h_q, Wo_qn, bo_qn, skip_qn, z_q, NQn);

    decoder_kernel<<<(2 * NLn * 32 + 255) / 256, 256, 0, stream>>>(
        z_q, z_a, pos_idx, neg_idx, (float*)d_out);
}

// Round 7
// 616.212 us; speedup vs baseline: 1.4288x; 1.2117x over previous
//
#include <hip/hip_runtime.h>

typedef unsigned short u16;
typedef __attribute__((ext_vector_type(8))) short short8;   // 8 bf16 = 4 VGPRs
typedef __attribute__((ext_vector_type(4))) float f32x4;

#define NQn 100000
#define NAn 200000
#define E1n 250000
#define E2n 250000
#define E3n 500000
#define NLn 100000
#define SLOTS 40   // max in-degree bucket capacity; Poisson(5) => P(>40) ~ 1e-22

__device__ __forceinline__ float bf2f(u16 u) {
    return __uint_as_float(((unsigned)u) << 16);
}
__device__ __forceinline__ float bf2f_lo(unsigned u) {
    return __uint_as_float(u << 16);
}
__device__ __forceinline__ float bf2f_hi(unsigned u) {
    return __uint_as_float(u & 0xffff0000u);
}
__device__ __forceinline__ u16 f2bf(float f) {
    unsigned x = __float_as_uint(f);
    unsigned r = (x + 0x7fffu + ((x >> 16) & 1u)) >> 16;
    return (u16)r;
}
__device__ __forceinline__ float sigmoidf_(float x) {
    return 1.f / (1.f + __expf(-x));
}

// -------- fold per-relation transforms into K/V weights (fp32 in, bf16 out) --------
// Wbig cols: [0,64): Wq ; [64,128): Wk@A(t0) ; [128,192): Wv@M(t0) ;
//            [192,256): Wk@A(t1) ; [256,320): Wv@M(t1)
__global__ void fold_kernel(
    const float* __restrict__ Wk, const float* __restrict__ Wv, const float* __restrict__ Wq,
    const float* __restrict__ bk, const float* __restrict__ bv, const float* __restrict__ bq,
    const float* __restrict__ a_rel, const float* __restrict__ m_rel,
    int t0, int t1, u16* __restrict__ Wbig, float* __restrict__ bbig, int NOUT)
{
    const int total = 65 * NOUT;   // 64 weight rows + 1 bias row
    for (int idx = blockIdx.x * blockDim.x + threadIdx.x; idx < total;
         idx += gridDim.x * blockDim.x) {
        const int c   = idx / NOUT;
        const int col = idx - c * NOUT;
        const int grp = col >> 6;
        const int oc  = col & 63;
        const int h   = oc >> 5, e = oc & 31;
        if (c < 64) {
            float val;
            if (grp == 0) {
                val = Wq[c * 64 + oc];
            } else {
                const int t = (grp <= 2) ? t0 : t1;
                const float* W = (grp & 1) ? Wk : Wv;
                const float* T = (grp & 1) ? a_rel : m_rel;
                float s = 0.f;
                for (int d = 0; d < 32; ++d)
                    s = fmaf(W[c * 64 + h * 32 + d],
                             T[((t * 2 + h) * 32 + d) * 32 + e], s);
                val = s;
            }
            Wbig[c * NOUT + col] = f2bf(val);
        } else {
            float val;
            if (grp == 0) {
                val = bq[oc];
            } else {
                const int t = (grp <= 2) ? t0 : t1;
                const float* B = (grp & 1) ? bk : bv;
                const float* T = (grp & 1) ? a_rel : m_rel;
                float s = 0.f;
                for (int d = 0; d < 32; ++d)
                    s = fmaf(B[h * 32 + d],
                             T[((t * 2 + h) * 32 + d) * 32 + e], s);
                val = s;
            }
            bbig[col] = val;
        }
    }
}

// -------- MFMA fused node projection --------------------------------------
template <int NOUT>
__global__ __launch_bounds__(256, 2) void node_mfma(
    const float* __restrict__ x, int N,
    const float* __restrict__ Win, const float* __restrict__ bin,
    const u16* __restrict__ Wbig, const float* __restrict__ bbig,
    u16* __restrict__ h_out, u16* __restrict__ big_out)
{
    constexpr int NT = NOUT / 16;            // stage-2 col tiles
    __shared__ __align__(16) short sB1[4 * 4 * 64 * 8];   // [kt][nt][lane][j], 16 KB
    __shared__ __align__(16) short sB2[2 * NT * 64 * 8];  // [kt2][nt][lane][j]
    __shared__ __align__(16) short sH[4][16 * 72];        // per-wave h tile, stride 72
    __shared__ float sb1[64];
    __shared__ float sb2[NOUT];

    const int tid = threadIdx.x;
    for (int idx = tid; idx < 4 * 4 * 64 * 8; idx += 256) {
        const int j = idx & 7;
        const int ln = (idx >> 3) & 63;
        const int f = idx >> 9;              // kt*4 + nt
        const int kt = f >> 2, nt = f & 3;
        const int k = kt * 32 + (ln >> 4) * 8 + j;
        const int n = nt * 16 + (ln & 15);
        sB1[idx] = (short)f2bf(Win[k * 64 + n]);
    }
    for (int idx = tid; idx < 2 * NT * 64 * 8; idx += 256) {
        const int j = idx & 7;
        const int ln = (idx >> 3) & 63;
        const int f = idx >> 9;              // kt2*NT + nt
        const int kt2 = f / NT, nt = f - kt2 * NT;
        const int k = kt2 * 32 + (ln >> 4) * 8 + j;
        const int n = nt * 16 + (ln & 15);
        sB2[idx] = (short)Wbig[k * NOUT + n];
    }
    if (tid < 64) sb1[tid] = bin[tid];
    for (int i = tid; i < NOUT; i += 256) sb2[i] = bbig[i];
    __syncthreads();

    const int wave = tid >> 6;
    const int lane = tid & 63;
    const int quad = lane >> 4;
    const int mrow = lane & 15;
    short* const myH = &sH[wave][0];

    const int ntiles = (N + 63) >> 6;
    for (int tile = blockIdx.x; tile < ntiles; tile += gridDim.x) {
        const int nbase = tile * 64 + wave * 16;
        const int node = nbase + mrow;

        short8 a1[4];
        if (node < N) {
            const float* xp = x + (size_t)node * 128 + quad * 8;
            #pragma unroll
            for (int kt = 0; kt < 4; ++kt) {
                const float4 u0 = *(const float4*)(xp + kt * 32);
                const float4 u1 = *(const float4*)(xp + kt * 32 + 4);
                short8 f;
                f[0] = (short)f2bf(u0.x); f[1] = (short)f2bf(u0.y);
                f[2] = (short)f2bf(u0.z); f[3] = (short)f2bf(u0.w);
                f[4] = (short)f2bf(u1.x); f[5] = (short)f2bf(u1.y);
                f[6] = (short)f2bf(u1.z); f[7] = (short)f2bf(u1.w);
                a1[kt] = f;
            }
        } else {
            #pragma unroll
            for (int kt = 0; kt < 4; ++kt) a1[kt] = short8{0,0,0,0,0,0,0,0};
        }

        #pragma unroll
        for (int nt = 0; nt < 4; ++nt) {
            const float bv = sb1[nt * 16 + mrow];
            f32x4 acc = {bv, bv, bv, bv};
            #pragma unroll
            for (int kt = 0; kt < 4; ++kt) {
                const short8 bf = *(const short8*)&sB1[((kt * 4 + nt) * 64 + lane) * 8];
                acc = __builtin_amdgcn_mfma_f32_16x16x32_bf16(a1[kt], bf, acc, 0, 0, 0);
            }
            #pragma unroll
            for (int r = 0; r < 4; ++r) {
                const int row = quad * 4 + r;
                const int nd = nbase + row;
                const u16 hb = f2bf(fmaxf(acc[r], 0.f));
                myH[row * 72 + nt * 16 + mrow] = (short)hb;
                if (nd < N) h_out[(size_t)nd * 64 + nt * 16 + mrow] = hb;
            }
        }

        short8 a2[2];
        #pragma unroll
        for (int kt2 = 0; kt2 < 2; ++kt2)
            a2[kt2] = *(const short8*)&myH[mrow * 72 + kt2 * 32 + quad * 8];

        for (int nt = 0; nt < NT; ++nt) {
            const float bv = sb2[nt * 16 + mrow];
            f32x4 acc = {bv, bv, bv, bv};
            const short8 b0 = *(const short8*)&sB2[((0 * NT + nt) * 64 + lane) * 8];
            acc = __builtin_amdgcn_mfma_f32_16x16x32_bf16(a2[0], b0, acc, 0, 0, 0);
            const short8 b1 = *(const short8*)&sB2[((1 * NT + nt) * 64 + lane) * 8];
            acc = __builtin_amdgcn_mfma_f32_16x16x32_bf16(a2[1], b1, acc, 0, 0, 0);
            #pragma unroll
            for (int r = 0; r < 4; ++r) {
                const int nd = nbase + quad * 4 + r;
                if (nd < N)
                    big_out[(size_t)nd * NOUT + nt * 16 + mrow] = f2bf(acc[r]);
            }
        }
    }
}

// -------- scatter: bucket edges by destination (no score computation) ------
// payload.x = (src*srcStride + kBase) | relBit   (k-offset, mult of 32; v = +64)
// payload.y = bits of per-edge weight w
__global__ __launch_bounds__(256) void scatter_kernel(
    const int* __restrict__ src, const int* __restrict__ dst, int E,
    int srcStride, int kBase, int relBit, const float* __restrict__ w,
    int* __restrict__ cursor, int2* __restrict__ payload)
{
    const int e = blockIdx.x * 256 + threadIdx.x;
    if (e >= E) return;
    const int s = src[e];
    const int d = dst[e];
    if ((unsigned)d >= (unsigned)NQn) return;   // guaranteed not to happen; memory safety
    const int slot = atomicAdd(&cursor[d], 1);
    if (slot < SLOTS)
        payload[(size_t)d * SLOTS + slot] =
            make_int2((s * srcStride + kBase) | relBit, __float_as_int(w[e]));
}

// -------- gather + softmax + gelu + MFMA-Wo + skip -------------------------
// r6 lesson: the per-node chain (cursor->payload->k-load->reduce) was serial
// over 16 nodes/wave => latency-bound. Now: one node per 16-LANE GROUP
// (4 concurrent chains/wave, 4 sub-rounds per 16-node tile). Each lane holds
// 4 channels (uint2 loads). Per-edge: group-uniform payload load (no shfl
// broadcast), 3x shfl_xor head-reduce (was 5 + 2 broadcasts). Epilogue MFMA
// (Wo frags resident in VGPRs) unchanged.
__global__ __launch_bounds__(256) void gather_finalize(
    const int* __restrict__ cursor, const int2* __restrict__ payload,
    const u16* __restrict__ srcArr,
    const u16* __restrict__ qArr, int qStride,
    const float* __restrict__ p_rel, int t0, int t1,
    const u16* __restrict__ h_in,
    const float* __restrict__ Wo, const float* __restrict__ bo,
    const float* __restrict__ skip, u16* __restrict__ z_out, int N)
{
    __shared__ __align__(16) short sWoF[8 * 64 * 8];   // [kt*4+nt][lane][j] bf16 frags, 8 KB
    __shared__ __align__(16) short sG[4][16 * 72];     // per-wave gelu rows (bf16)
    __shared__ __align__(16) short sHh[4][16 * 72];    // per-wave h rows (raw bf16)
    __shared__ float sbo[64];

    const int tid = threadIdx.x;
    for (int idx = tid; idx < 8 * 64 * 8; idx += 256) {
        const int j = idx & 7;
        const int ln = (idx >> 3) & 63;
        const int f = idx >> 9;              // kt*4 + nt
        const int kt = f >> 2, nt = f & 3;
        const int k = kt * 32 + (ln >> 4) * 8 + j;
        const int n = nt * 16 + (ln & 15);
        sWoF[idx] = (short)f2bf(Wo[k * 64 + n]);
    }
    if (tid < 64) sbo[tid] = bo[tid];
    __syncthreads();

    const int wave = tid >> 6, lane = tid & 63;
    const int quad = lane >> 4, mrow = lane & 15;
    const int grp = lane >> 4;       // node group 0..3
    const int gl = lane & 15;        // lane within group; holds channels 4gl..4gl+3
    const int ghead = gl >> 3;       // head of this lane's channels

    // Wo B-fragments resident in VGPRs (8 x short8 = 32 VGPRs)
    short8 bw[8];
    #pragma unroll
    for (int f = 0; f < 8; ++f)
        bw[f] = *(const short8*)&sWoF[(f * 64 + lane) * 8];

    const float sk = sigmoidf_(skip[0]);
    const float isq = 0.17677669529663687f;   // 1/sqrt(32)
    const float s0 = p_rel[t0 * 2 + ghead] * isq;
    const float s1 = p_rel[t1 * 2 + ghead] * isq;

    short* const myG = &sG[wave][0];
    short* const myHh = &sHh[wave][0];

    const int ntiles = (N + 63) >> 6;
    for (int tile = blockIdx.x; tile < ntiles; tile += gridDim.x) {
        const int nbase = tile * 64 + wave * 16;

        #pragma unroll
        for (int sub = 0; sub < 4; ++sub) {
            const int nl = sub * 4 + grp;
            const int node = nbase + nl;
            const bool valid = node < N;
            int cnt = 0;
            uint2 qraw = make_uint2(0, 0), hraw = make_uint2(0, 0);
            if (valid) {
                cnt = (node < NQn) ? cursor[node] : 0;
                if (cnt > SLOTS) cnt = SLOTS;
                qraw = *(const uint2*)(qArr + (size_t)node * qStride + gl * 4);
                hraw = *(const uint2*)(h_in + (size_t)node * 64 + gl * 4);
            }
            const float qv0 = bf2f_lo(qraw.x), qv1 = bf2f_hi(qraw.x);
            const float qv2 = bf2f_lo(qraw.y), qv3 = bf2f_hi(qraw.y);

            float a0 = 0.f, a1 = 0.f, a2 = 0.f, a3 = 0.f, den = 0.f;
            for (int i = 0; i < cnt; ++i) {
                const int2 e = payload[(size_t)node * SLOTS + i];  // group-uniform
                const int koff = e.x & ~31;
                const uint2 kraw = *(const uint2*)(srcArr + (size_t)koff + gl * 4);
                const uint2 vraw = *(const uint2*)(srcArr + (size_t)koff + 64 + gl * 4);
                float p = qv0 * bf2f_lo(kraw.x) + qv1 * bf2f_hi(kraw.x)
                        + qv2 * bf2f_lo(kraw.y) + qv3 * bf2f_hi(kraw.y);
                p += __shfl_xor(p, 1);     // reduce over the 8 lanes of this head
                p += __shfl_xor(p, 2);
                p += __shfl_xor(p, 4);
                const float sc = (e.x & 1) ? s1 : s0;
                const float exv = __expf(p * sc);
                const float ew = exv * __int_as_float(e.y);
                a0 = fmaf(ew, bf2f_lo(vraw.x), a0);
                a1 = fmaf(ew, bf2f_hi(vraw.x), a1);
                a2 = fmaf(ew, bf2f_lo(vraw.y), a2);
                a3 = fmaf(ew, bf2f_hi(vraw.y), a3);
                den += exv;
            }

            const float inv = 1.f / (den + 1e-16f);
            float gv[4] = {a0 * inv, a1 * inv, a2 * inv, a3 * inv};
            unsigned gp[2];
            #pragma unroll
            for (int j = 0; j < 4; ++j) {
                const float xx = gv[j];
                const float u = 0.7978845608028654f * (xx + 0.044715f * xx * xx * xx);
                const float th = 1.f - 2.f / (__expf(2.f * u) + 1.f);
                gv[j] = 0.5f * xx * (1.f + th);
            }
            gp[0] = (unsigned)f2bf(gv[0]) | ((unsigned)f2bf(gv[1]) << 16);
            gp[1] = (unsigned)f2bf(gv[2]) | ((unsigned)f2bf(gv[3]) << 16);
            *(uint2*)&myG[nl * 72 + gl * 4] = make_uint2(gp[0], gp[1]);
            *(uint2*)&myHh[nl * 72 + gl * 4] = hraw;
        }

        // wave-private MFMA: Z16x64 = G16x64 @ Wo64x64 (+bo), then skip blend
        short8 ag[2];
        #pragma unroll
        for (int kt = 0; kt < 2; ++kt)
            ag[kt] = *(const short8*)&myG[mrow * 72 + kt * 32 + quad * 8];

        #pragma unroll
        for (int nt = 0; nt < 4; ++nt) {
            const float bov = sbo[nt * 16 + mrow];
            f32x4 acc = {bov, bov, bov, bov};
            acc = __builtin_amdgcn_mfma_f32_16x16x32_bf16(ag[0], bw[nt], acc, 0, 0, 0);
            acc = __builtin_amdgcn_mfma_f32_16x16x32_bf16(ag[1], bw[4 + nt], acc, 0, 0, 0);
            #pragma unroll
            for (int r = 0; r < 4; ++r) {
                const int row = quad * 4 + r;
                const int node = nbase + row;
                if (node < N) {
                    const float hv = bf2f((u16)myHh[row * 72 + nt * 16 + mrow]);
                    z_out[(size_t)node * 64 + nt * 16 + mrow] =
                        f2bf(sk * acc[r] + (1.f - sk) * hv);
                }
            }
        }
    }
}

// -------- decoder: sigmoid(dot64) link prediction --------------------------
__global__ __launch_bounds__(256) void decoder_kernel(
    const u16* __restrict__ z_q, const u16* __restrict__ z_a,
    const int* __restrict__ pos_idx, const int* __restrict__ neg_idx,
    float* __restrict__ out)
{
    const int gid = blockIdx.x * 256 + threadIdx.x;
    const int o = gid >> 5;         // half-wave per output
    if (o >= 2 * NLn) return;
    const int lane = threadIdx.x & 31;
    const int* idx;
    int i;
    if (o < NLn) { idx = pos_idx; i = o; }
    else         { idx = neg_idx; i = o - NLn; }
    const int r0 = idx[i];
    const int r1 = idx[NLn + i];
    float s = bf2f(z_q[(size_t)r0 * 64 + 2 * lane])     * bf2f(z_a[(size_t)r1 * 64 + 2 * lane])
            + bf2f(z_q[(size_t)r0 * 64 + 2 * lane + 1]) * bf2f(z_a[(size_t)r1 * 64 + 2 * lane + 1]);
    s += __shfl_xor(s, 16);
    s += __shfl_xor(s, 8);
    s += __shfl_xor(s, 4);
    s += __shfl_xor(s, 2);
    s += __shfl_xor(s, 1);
    if (lane == 0) out[o] = sigmoidf_(s);
}

extern "C" void kernel_launch(void* const* d_in, const int* in_sizes, int n_in,
                              void* d_out, int out_size, void* d_ws, size_t ws_size,
                              hipStream_t stream)
{
    (void)in_sizes; (void)n_in; (void)out_size;
    const float* x_q   = (const float*)d_in[0];
    const float* x_a   = (const float*)d_in[1];
    const int* ei_qca  = (const int*)d_in[2];
    const int* ei_qwa  = (const int*)d_in[3];
    const int* ei_rev  = (const int*)d_in[4];
    const int* pos_idx = (const int*)d_in[5];
    const int* neg_idx = (const int*)d_in[6];
    const float* w_qca = (const float*)d_in[7];
    const float* w_qwa = (const float*)d_in[8];
    const float* w_rev = (const float*)d_in[9];
    const float* W_in_q = (const float*)d_in[10]; const float* b_in_q = (const float*)d_in[11];
    const float* W_in_a = (const float*)d_in[12]; const float* b_in_a = (const float*)d_in[13];
    const float* Wk_qn = (const float*)d_in[14], *bk_qn = (const float*)d_in[15];
    const float* Wq_qn = (const float*)d_in[16], *bq_qn = (const float*)d_in[17];
    const float* Wv_qn = (const float*)d_in[18], *bv_qn = (const float*)d_in[19];
    const float* Wk_an = (const float*)d_in[20], *bk_an = (const float*)d_in[21];
    const float* Wq_an = (const float*)d_in[22], *bq_an = (const float*)d_in[23];
    const float* Wv_an = (const float*)d_in[24], *bv_an = (const float*)d_in[25];
    const float* a_rel = (const float*)d_in[26];
    const float* m_rel = (const float*)d_in[27];
    const float* p_rel = (const float*)d_in[28];
    const float* Wo_qn = (const float*)d_in[29], *bo_qn = (const float*)d_in[30];
    const float* Wo_an = (const float*)d_in[31], *bo_an = (const float*)d_in[32];
    const float* skip_qn = (const float*)d_in[33], *skip_an = (const float*)d_in[34];

    char* ws = (char*)d_ws;
    size_t off = 0;
    auto alloc = [&](size_t bytes) -> char* {
        char* p = ws + off;
        off = (off + bytes + 255) & ~(size_t)255;
        return p;
    };
    u16* big_q = (u16*)alloc((size_t)NQn * 320 * 2);  // q | k0 | v0 | k1 | v1
    u16* big_a = (u16*)alloc((size_t)NAn * 192 * 2);  // q | k2 | v2
    u16* h_q   = (u16*)alloc((size_t)NQn * 64 * 2);
    u16* h_a   = (u16*)alloc((size_t)NAn * 64 * 2);
    u16* z_q   = (u16*)alloc((size_t)NQn * 64 * 2);
    u16* z_a   = (u16*)alloc((size_t)NAn * 64 * 2);
    int2* payload_a = (int2*)alloc((size_t)NQn * SLOTS * 8);  // dst of E1/E2 < NQn
    int2* payload_q = (int2*)alloc((size_t)NQn * SLOTS * 8);
    char* zero_start = ws + off;
    int* cursor_a = (int*)alloc((size_t)NQn * 4);
    int* cursor_q = (int*)alloc((size_t)NQn * 4);
    char* zero_end = ws + off;
    u16* Wbig_q = (u16*)alloc(64 * 320 * 2);
    float* bbig_q = (float*)alloc(320 * 4);
    u16* Wbig_a = (u16*)alloc(64 * 192 * 2);
    float* bbig_a = (float*)alloc(192 * 4);

    if (off > ws_size) return;  // workspace too small: leave output zeroed (visible failure)

    hipMemsetAsync(zero_start, 0, (size_t)(zero_end - zero_start), stream);

    fold_kernel<<<64, 256, 0, stream>>>(Wk_qn, Wv_qn, Wq_qn, bk_qn, bv_qn, bq_qn,
                                        a_rel, m_rel, 0, 1, Wbig_q, bbig_q, 320);
    fold_kernel<<<64, 256, 0, stream>>>(Wk_an, Wv_an, Wq_an, bk_an, bv_an, bq_an,
                                        a_rel, m_rel, 2, -1, Wbig_a, bbig_a, 192);

    node_mfma<320><<<512, 256, 0, stream>>>(x_q, NQn, W_in_q, b_in_q, Wbig_q, bbig_q, h_q, big_q);
    node_mfma<192><<<512, 256, 0, stream>>>(x_a, NAn, W_in_a, b_in_a, Wbig_a, bbig_a, h_a, big_a);

    scatter_kernel<<<(E1n + 255) / 256, 256, 0, stream>>>(
        ei_qca, ei_qca + E1n, E1n, 320, 64, 0, w_qca, cursor_a, payload_a);
    scatter_kernel<<<(E2n + 255) / 256, 256, 0, stream>>>(
        ei_qwa, ei_qwa + E2n, E2n, 320, 192, 1, w_qwa, cursor_a, payload_a);
    scatter_kernel<<<(E3n + 255) / 256, 256, 0, stream>>>(
        ei_rev, ei_rev + E3n, E3n, 192, 64, 0, w_rev, cursor_q, payload_q);

    // answer-node aggregation: edges from q-nodes (big_q), q rows in big_a
    gather_finalize<<<3136, 256, 0, stream>>>(
        cursor_a, payload_a, big_q, big_a, 192, p_rel, 0, 1,
        h_a, Wo_an, bo_an, skip_an, z_a, NAn);
    // question-node aggregation: edges from a-nodes (big_a), q rows in big_q
    gather_finalize<<<1568, 256, 0, stream>>>(
        cursor_q, payload_q, big_a, big_q, 320, p_rel, 2, 2,
        h_q, Wo_qn, bo_qn, skip_qn, z_q, NQn);

    decoder_kernel<<<(2 * NLn * 32 + 255) / 256, 256, 0, stream>>>(
        z_q, z_a, pos_idx, neg_idx, (float*)d_out);
}

// Round 8
// 584.571 us; speedup vs baseline: 1.5061x; 1.0541x over previous
//
#include <hip/hip_runtime.h>

typedef unsigned short u16;
typedef __attribute__((ext_vector_type(8))) short short8;   // 8 bf16 = 4 VGPRs
typedef __attribute__((ext_vector_type(4))) float f32x4;

#define NQn 100000
#define NAn 200000
#define E1n 250000
#define E2n 250000
#define E3n 500000
#define NLn 100000
#define SLOTS 40   // max in-degree bucket capacity; Poisson(5) => P(>40) ~ 1e-22

__device__ __forceinline__ float bf2f(u16 u) {
    return __uint_as_float(((unsigned)u) << 16);
}
__device__ __forceinline__ float bf2f_lo(unsigned u) {
    return __uint_as_float(u << 16);
}
__device__ __forceinline__ float bf2f_hi(unsigned u) {
    return __uint_as_float(u & 0xffff0000u);
}
__device__ __forceinline__ u16 f2bf(float f) {
    unsigned x = __float_as_uint(f);
    unsigned r = (x + 0x7fffu + ((x >> 16) & 1u)) >> 16;
    return (u16)r;
}
__device__ __forceinline__ float sigmoidf_(float x) {
    return 1.f / (1.f + __expf(-x));
}

// -------- fold per-relation transforms into K/V weights (fp32 in, bf16 out) --------
// Wbig cols: [0,64): Wq ; [64,128): Wk@A(t0) ; [128,192): Wv@M(t0) ;
//            [192,256): Wk@A(t1) ; [256,320): Wv@M(t1)
__global__ void fold_kernel(
    const float* __restrict__ Wk, const float* __restrict__ Wv, const float* __restrict__ Wq,
    const float* __restrict__ bk, const float* __restrict__ bv, const float* __restrict__ bq,
    const float* __restrict__ a_rel, const float* __restrict__ m_rel,
    int t0, int t1, u16* __restrict__ Wbig, float* __restrict__ bbig, int NOUT)
{
    const int total = 65 * NOUT;   // 64 weight rows + 1 bias row
    for (int idx = blockIdx.x * blockDim.x + threadIdx.x; idx < total;
         idx += gridDim.x * blockDim.x) {
        const int c   = idx / NOUT;
        const int col = idx - c * NOUT;
        const int grp = col >> 6;
        const int oc  = col & 63;
        const int h   = oc >> 5, e = oc & 31;
        if (c < 64) {
            float val;
            if (grp == 0) {
                val = Wq[c * 64 + oc];
            } else {
                const int t = (grp <= 2) ? t0 : t1;
                const float* W = (grp & 1) ? Wk : Wv;
                const float* T = (grp & 1) ? a_rel : m_rel;
                float s = 0.f;
                for (int d = 0; d < 32; ++d)
                    s = fmaf(W[c * 64 + h * 32 + d],
                             T[((t * 2 + h) * 32 + d) * 32 + e], s);
                val = s;
            }
            Wbig[c * NOUT + col] = f2bf(val);
        } else {
            float val;
            if (grp == 0) {
                val = bq[oc];
            } else {
                const int t = (grp <= 2) ? t0 : t1;
                const float* B = (grp & 1) ? bk : bv;
                const float* T = (grp & 1) ? a_rel : m_rel;
                float s = 0.f;
                for (int d = 0; d < 32; ++d)
                    s = fmaf(B[h * 32 + d],
                             T[((t * 2 + h) * 32 + d) * 32 + e], s);
                val = s;
            }
            bbig[col] = val;
        }
    }
}

// -------- MFMA fused node projection --------------------------------------
// r7 lesson: 64 scalar 2-B scattered stores/wave-tile serialize the CU's
// store-address pipe (~1 addr/cyc => ~16k cyc/tile). All outputs now staged
// in the per-wave LDS tile and written as coalesced dwordx4.
template <int NOUT>
__global__ __launch_bounds__(256, 2) void node_mfma(
    const float* __restrict__ x, int N,
    const float* __restrict__ Win, const float* __restrict__ bin,
    const u16* __restrict__ Wbig, const float* __restrict__ bbig,
    u16* __restrict__ h_out, u16* __restrict__ big_out)
{
    constexpr int NT = NOUT / 16;            // stage-2 col tiles
    constexpr int NG = NT / 4;               // stage-2 64-col store groups
    __shared__ __align__(16) short sB1[4 * 4 * 64 * 8];   // [kt][nt][lane][j], 16 KB
    __shared__ __align__(16) short sB2[2 * NT * 64 * 8];  // [kt2][nt][lane][j]
    __shared__ __align__(16) short sH[4][16 * 72];        // per-wave tile, stride 72
    __shared__ float sb1[64];
    __shared__ float sb2[NOUT];

    const int tid = threadIdx.x;
    for (int idx = tid; idx < 4 * 4 * 64 * 8; idx += 256) {
        const int j = idx & 7;
        const int ln = (idx >> 3) & 63;
        const int f = idx >> 9;              // kt*4 + nt
        const int kt = f >> 2, nt = f & 3;
        const int k = kt * 32 + (ln >> 4) * 8 + j;
        const int n = nt * 16 + (ln & 15);
        sB1[idx] = (short)f2bf(Win[k * 64 + n]);
    }
    for (int idx = tid; idx < 2 * NT * 64 * 8; idx += 256) {
        const int j = idx & 7;
        const int ln = (idx >> 3) & 63;
        const int f = idx >> 9;              // kt2*NT + nt
        const int kt2 = f / NT, nt = f - kt2 * NT;
        const int k = kt2 * 32 + (ln >> 4) * 8 + j;
        const int n = nt * 16 + (ln & 15);
        sB2[idx] = (short)Wbig[k * NOUT + n];
    }
    if (tid < 64) sb1[tid] = bin[tid];
    for (int i = tid; i < NOUT; i += 256) sb2[i] = bbig[i];
    __syncthreads();

    const int wave = tid >> 6;
    const int lane = tid & 63;
    const int quad = lane >> 4;
    const int mrow = lane & 15;
    short* const myH = &sH[wave][0];
    const int srow = lane >> 2;              // store-phase row
    const int scol = (lane & 3) * 16;        // store-phase col base

    const int ntiles = (N + 63) >> 6;
    for (int tile = blockIdx.x; tile < ntiles; tile += gridDim.x) {
        const int nbase = tile * 64 + wave * 16;
        const int node = nbase + mrow;
        const bool fullgrp = (nbase + 16 <= N);

        short8 a1[4];
        if (node < N) {
            const float* xp = x + (size_t)node * 128 + quad * 8;
            #pragma unroll
            for (int kt = 0; kt < 4; ++kt) {
                const float4 u0 = *(const float4*)(xp + kt * 32);
                const float4 u1 = *(const float4*)(xp + kt * 32 + 4);
                short8 f;
                f[0] = (short)f2bf(u0.x); f[1] = (short)f2bf(u0.y);
                f[2] = (short)f2bf(u0.z); f[3] = (short)f2bf(u0.w);
                f[4] = (short)f2bf(u1.x); f[5] = (short)f2bf(u1.y);
                f[6] = (short)f2bf(u1.z); f[7] = (short)f2bf(u1.w);
                a1[kt] = f;
            }
        } else {
            #pragma unroll
            for (int kt = 0; kt < 4; ++kt) a1[kt] = short8{0,0,0,0,0,0,0,0};
        }

        // ---- stage 1: h = relu(x@Win + b1) -> myH ----
        #pragma unroll
        for (int nt = 0; nt < 4; ++nt) {
            const float bv = sb1[nt * 16 + mrow];
            f32x4 acc = {bv, bv, bv, bv};
            #pragma unroll
            for (int kt = 0; kt < 4; ++kt) {
                const short8 bf = *(const short8*)&sB1[((kt * 4 + nt) * 64 + lane) * 8];
                acc = __builtin_amdgcn_mfma_f32_16x16x32_bf16(a1[kt], bf, acc, 0, 0, 0);
            }
            #pragma unroll
            for (int r = 0; r < 4; ++r)
                myH[(quad * 4 + r) * 72 + nt * 16 + mrow] =
                    (short)f2bf(fmaxf(acc[r], 0.f));
        }

        // ---- coalesced h store: 16 rows x 128 B = 2 KB contiguous ----
        if (fullgrp) {
            const uint4 w0 = *(const uint4*)&myH[srow * 72 + scol];
            const uint4 w1 = *(const uint4*)&myH[srow * 72 + scol + 8];
            *(uint4*)(h_out + (size_t)nbase * 64 + (size_t)lane * 16) = w0;
            *(uint4*)(h_out + (size_t)nbase * 64 + (size_t)lane * 16 + 8) = w1;
        } else {
            for (int e = lane; e < 16 * 64; e += 64) {
                const int r = e >> 6, c = e & 63;
                const int nd = nbase + r;
                if (nd < N) h_out[(size_t)nd * 64 + c] = (u16)myH[r * 72 + c];
            }
        }

        // ---- stage 2: big = h @ Wbig + b2, grouped 64-col staging ----
        short8 a2[2];
        #pragma unroll
        for (int kt2 = 0; kt2 < 2; ++kt2)
            a2[kt2] = *(const short8*)&myH[mrow * 72 + kt2 * 32 + quad * 8];

        #pragma unroll
        for (int g = 0; g < NG; ++g) {
            #pragma unroll
            for (int q2 = 0; q2 < 4; ++q2) {
                const int nt = g * 4 + q2;
                const float bv = sb2[nt * 16 + mrow];
                f32x4 acc = {bv, bv, bv, bv};
                const short8 b0 = *(const short8*)&sB2[((0 * NT + nt) * 64 + lane) * 8];
                acc = __builtin_amdgcn_mfma_f32_16x16x32_bf16(a2[0], b0, acc, 0, 0, 0);
                const short8 b1 = *(const short8*)&sB2[((1 * NT + nt) * 64 + lane) * 8];
                acc = __builtin_amdgcn_mfma_f32_16x16x32_bf16(a2[1], b1, acc, 0, 0, 0);
                #pragma unroll
                for (int r = 0; r < 4; ++r)
                    myH[(quad * 4 + r) * 72 + q2 * 16 + mrow] = (short)f2bf(acc[r]);
            }
            if (fullgrp) {
                const uint4 w0 = *(const uint4*)&myH[srow * 72 + scol];
                const uint4 w1 = *(const uint4*)&myH[srow * 72 + scol + 8];
                u16* dst = big_out + (size_t)(nbase + srow) * NOUT + g * 64 + scol;
                *(uint4*)dst = w0;
                *(uint4*)(dst + 8) = w1;
            } else {
                for (int e = lane; e < 16 * 64; e += 64) {
                    const int r = e >> 6, c = e & 63;
                    const int nd = nbase + r;
                    if (nd < N)
                        big_out[(size_t)nd * NOUT + g * 64 + c] = (u16)myH[r * 72 + c];
                }
            }
        }
    }
}

// -------- scatter: bucket edges by destination (no score computation) ------
// payload.x = (src*srcStride + kBase) | relBit   (k-offset, mult of 32; v = +64)
// payload.y = bits of per-edge weight w
__global__ __launch_bounds__(256) void scatter_kernel(
    const int* __restrict__ src, const int* __restrict__ dst, int E,
    int srcStride, int kBase, int relBit, const float* __restrict__ w,
    int* __restrict__ cursor, int2* __restrict__ payload)
{
    const int e = blockIdx.x * 256 + threadIdx.x;
    if (e >= E) return;
    const int s = src[e];
    const int d = dst[e];
    if ((unsigned)d >= (unsigned)NQn) return;   // guaranteed not to happen; memory safety
    const int slot = atomicAdd(&cursor[d], 1);
    if (slot < SLOTS)
        payload[(size_t)d * SLOTS + slot] =
            make_int2((s * srcStride + kBase) | relBit, __float_as_int(w[e]));
}

// -------- gather + softmax + gelu + MFMA-Wo + skip -------------------------
// One node per 16-lane group (4 concurrent chains/wave). Epilogue MFMA with
// Wo frags in VGPRs; z staged in LDS then stored coalesced (r7 store fix).
__global__ __launch_bounds__(256) void gather_finalize(
    const int* __restrict__ cursor, const int2* __restrict__ payload,
    const u16* __restrict__ srcArr,
    const u16* __restrict__ qArr, int qStride,
    const float* __restrict__ p_rel, int t0, int t1,
    const u16* __restrict__ h_in,
    const float* __restrict__ Wo, const float* __restrict__ bo,
    const float* __restrict__ skip, u16* __restrict__ z_out, int N)
{
    __shared__ __align__(16) short sWoF[8 * 64 * 8];   // [kt*4+nt][lane][j] bf16 frags, 8 KB
    __shared__ __align__(16) short sG[4][16 * 72];     // per-wave gelu rows (bf16)
    __shared__ __align__(16) short sHh[4][16 * 72];    // per-wave h rows -> z rows
    __shared__ float sbo[64];

    const int tid = threadIdx.x;
    for (int idx = tid; idx < 8 * 64 * 8; idx += 256) {
        const int j = idx & 7;
        const int ln = (idx >> 3) & 63;
        const int f = idx >> 9;              // kt*4 + nt
        const int kt = f >> 2, nt = f & 3;
        const int k = kt * 32 + (ln >> 4) * 8 + j;
        const int n = nt * 16 + (ln & 15);
        sWoF[idx] = (short)f2bf(Wo[k * 64 + n]);
    }
    if (tid < 64) sbo[tid] = bo[tid];
    __syncthreads();

    const int wave = tid >> 6, lane = tid & 63;
    const int quad = lane >> 4, mrow = lane & 15;
    const int grp = lane >> 4;       // node group 0..3
    const int gl = lane & 15;        // lane within group; holds channels 4gl..4gl+3
    const int ghead = gl >> 3;       // head of this lane's channels
    const int srow = lane >> 2;      // store-phase row
    const int scol = (lane & 3) * 16;

    // Wo B-fragments resident in VGPRs (8 x short8 = 32 VGPRs)
    short8 bw[8];
    #pragma unroll
    for (int f = 0; f < 8; ++f)
        bw[f] = *(const short8*)&sWoF[(f * 64 + lane) * 8];

    const float sk = sigmoidf_(skip[0]);
    const float isq = 0.17677669529663687f;   // 1/sqrt(32)
    const float s0 = p_rel[t0 * 2 + ghead] * isq;
    const float s1 = p_rel[t1 * 2 + ghead] * isq;

    short* const myG = &sG[wave][0];
    short* const myHh = &sHh[wave][0];

    const int ntiles = (N + 63) >> 6;
    for (int tile = blockIdx.x; tile < ntiles; tile += gridDim.x) {
        const int nbase = tile * 64 + wave * 16;

        #pragma unroll
        for (int sub = 0; sub < 4; ++sub) {
            const int nl = sub * 4 + grp;
            const int node = nbase + nl;
            const bool valid = node < N;
            int cnt = 0;
            uint2 qraw = make_uint2(0, 0), hraw = make_uint2(0, 0);
            if (valid) {
                cnt = (node < NQn) ? cursor[node] : 0;
                if (cnt > SLOTS) cnt = SLOTS;
                qraw = *(const uint2*)(qArr + (size_t)node * qStride + gl * 4);
                hraw = *(const uint2*)(h_in + (size_t)node * 64 + gl * 4);
            }
            const float qv0 = bf2f_lo(qraw.x), qv1 = bf2f_hi(qraw.x);
            const float qv2 = bf2f_lo(qraw.y), qv3 = bf2f_hi(qraw.y);

            float a0 = 0.f, a1 = 0.f, a2 = 0.f, a3 = 0.f, den = 0.f;
            for (int i = 0; i < cnt; ++i) {
                const int2 e = payload[(size_t)node * SLOTS + i];  // group-uniform
                const int koff = e.x & ~31;
                const uint2 kraw = *(const uint2*)(srcArr + (size_t)koff + gl * 4);
                const uint2 vraw = *(const uint2*)(srcArr + (size_t)koff + 64 + gl * 4);
                float p = qv0 * bf2f_lo(kraw.x) + qv1 * bf2f_hi(kraw.x)
                        + qv2 * bf2f_lo(kraw.y) + qv3 * bf2f_hi(kraw.y);
                p += __shfl_xor(p, 1);     // reduce over the 8 lanes of this head
                p += __shfl_xor(p, 2);
                p += __shfl_xor(p, 4);
                const float sc = (e.x & 1) ? s1 : s0;
                const float exv = __expf(p * sc);
                const float ew = exv * __int_as_float(e.y);
                a0 = fmaf(ew, bf2f_lo(vraw.x), a0);
                a1 = fmaf(ew, bf2f_hi(vraw.x), a1);
                a2 = fmaf(ew, bf2f_lo(vraw.y), a2);
                a3 = fmaf(ew, bf2f_hi(vraw.y), a3);
                den += exv;
            }

            const float inv = 1.f / (den + 1e-16f);
            float gv[4] = {a0 * inv, a1 * inv, a2 * inv, a3 * inv};
            unsigned gp[2];
            #pragma unroll
            for (int j = 0; j < 4; ++j) {
                const float xx = gv[j];
                const float u = 0.7978845608028654f * (xx + 0.044715f * xx * xx * xx);
                const float th = 1.f - 2.f / (__expf(2.f * u) + 1.f);
                gv[j] = 0.5f * xx * (1.f + th);
            }
            gp[0] = (unsigned)f2bf(gv[0]) | ((unsigned)f2bf(gv[1]) << 16);
            gp[1] = (unsigned)f2bf(gv[2]) | ((unsigned)f2bf(gv[3]) << 16);
            *(uint2*)&myG[nl * 72 + gl * 4] = make_uint2(gp[0], gp[1]);
            *(uint2*)&myHh[nl * 72 + gl * 4] = hraw;
        }

        // wave-private MFMA: Z16x64 = G16x64 @ Wo64x64 (+bo), skip blend -> myHh
        short8 ag[2];
        #pragma unroll
        for (int kt = 0; kt < 2; ++kt)
            ag[kt] = *(const short8*)&myG[mrow * 72 + kt * 32 + quad * 8];

        #pragma unroll
        for (int nt = 0; nt < 4; ++nt) {
            const float bov = sbo[nt * 16 + mrow];
            f32x4 acc = {bov, bov, bov, bov};
            acc = __builtin_amdgcn_mfma_f32_16x16x32_bf16(ag[0], bw[nt], acc, 0, 0, 0);
            acc = __builtin_amdgcn_mfma_f32_16x16x32_bf16(ag[1], bw[4 + nt], acc, 0, 0, 0);
            #pragma unroll
            for (int r = 0; r < 4; ++r) {
                const int row = quad * 4 + r;
                const int a = row * 72 + nt * 16 + mrow;
                const float hv = bf2f((u16)myHh[a]);
                myHh[a] = (short)f2bf(sk * acc[r] + (1.f - sk) * hv);
            }
        }

        // coalesced z store: 16 rows x 128 B = 2 KB contiguous
        if (nbase + 16 <= N) {
            const uint4 w0 = *(const uint4*)&myHh[srow * 72 + scol];
            const uint4 w1 = *(const uint4*)&myHh[srow * 72 + scol + 8];
            *(uint4*)(z_out + (size_t)nbase * 64 + (size_t)lane * 16) = w0;
            *(uint4*)(z_out + (size_t)nbase * 64 + (size_t)lane * 16 + 8) = w1;
        } else {
            for (int e = lane; e < 16 * 64; e += 64) {
                const int r = e >> 6, c = e & 63;
                const int nd = nbase + r;
                if (nd < N) z_out[(size_t)nd * 64 + c] = (u16)myHh[r * 72 + c];
            }
        }
    }
}

// -------- decoder: sigmoid(dot64) link prediction --------------------------
__global__ __launch_bounds__(256) void decoder_kernel(
    const u16* __restrict__ z_q, const u16* __restrict__ z_a,
    const int* __restrict__ pos_idx, const int* __restrict__ neg_idx,
    float* __restrict__ out)
{
    const int gid = blockIdx.x * 256 + threadIdx.x;
    const int o = gid >> 5;         // half-wave per output
    if (o >= 2 * NLn) return;
    const int lane = threadIdx.x & 31;
    const int* idx;
    int i;
    if (o < NLn) { idx = pos_idx; i = o; }
    else         { idx = neg_idx; i = o - NLn; }
    const int r0 = idx[i];
    const int r1 = idx[NLn + i];
    const unsigned uq = *(const unsigned*)(z_q + (size_t)r0 * 64 + 2 * lane);
    const unsigned ua = *(const unsigned*)(z_a + (size_t)r1 * 64 + 2 * lane);
    float s = bf2f_lo(uq) * bf2f_lo(ua) + bf2f_hi(uq) * bf2f_hi(ua);
    s += __shfl_xor(s, 16);
    s += __shfl_xor(s, 8);
    s += __shfl_xor(s, 4);
    s += __shfl_xor(s, 2);
    s += __shfl_xor(s, 1);
    if (lane == 0) out[o] = sigmoidf_(s);
}

extern "C" void kernel_launch(void* const* d_in, const int* in_sizes, int n_in,
                              void* d_out, int out_size, void* d_ws, size_t ws_size,
                              hipStream_t stream)
{
    (void)in_sizes; (void)n_in; (void)out_size;
    const float* x_q   = (const float*)d_in[0];
    const float* x_a   = (const float*)d_in[1];
    const int* ei_qca  = (const int*)d_in[2];
    const int* ei_qwa  = (const int*)d_in[3];
    const int* ei_rev  = (const int*)d_in[4];
    const int* pos_idx = (const int*)d_in[5];
    const int* neg_idx = (const int*)d_in[6];
    const float* w_qca = (const float*)d_in[7];
    const float* w_qwa = (const float*)d_in[8];
    const float* w_rev = (const float*)d_in[9];
    const float* W_in_q = (const float*)d_in[10]; const float* b_in_q = (const float*)d_in[11];
    const float* W_in_a = (const float*)d_in[12]; const float* b_in_a = (const float*)d_in[13];
    const float* Wk_qn = (const float*)d_in[14], *bk_qn = (const float*)d_in[15];
    const float* Wq_qn = (const float*)d_in[16], *bq_qn = (const float*)d_in[17];
    const float* Wv_qn = (const float*)d_in[18], *bv_qn = (const float*)d_in[19];
    const float* Wk_an = (const float*)d_in[20], *bk_an = (const float*)d_in[21];
    const float* Wq_an = (const float*)d_in[22], *bq_an = (const float*)d_in[23];
    const float* Wv_an = (const float*)d_in[24], *bv_an = (const float*)d_in[25];
    const float* a_rel = (const float*)d_in[26];
    const float* m_rel = (const float*)d_in[27];
    const float* p_rel = (const float*)d_in[28];
    const float* Wo_qn = (const float*)d_in[29], *bo_qn = (const float*)d_in[30];
    const float* Wo_an = (const float*)d_in[31], *bo_an = (const float*)d_in[32];
    const float* skip_qn = (const float*)d_in[33], *skip_an = (const float*)d_in[34];

    char* ws = (char*)d_ws;
    size_t off = 0;
    auto alloc = [&](size_t bytes) -> char* {
        char* p = ws + off;
        off = (off + bytes + 255) & ~(size_t)255;
        return p;
    };
    u16* big_q = (u16*)alloc((size_t)NQn * 320 * 2);  // q | k0 | v0 | k1 | v1
    u16* big_a = (u16*)alloc((size_t)NAn * 192 * 2);  // q | k2 | v2
    u16* h_q   = (u16*)alloc((size_t)NQn * 64 * 2);
    u16* h_a   = (u16*)alloc((size_t)NAn * 64 * 2);
    u16* z_q   = (u16*)alloc((size_t)NQn * 64 * 2);
    u16* z_a   = (u16*)alloc((size_t)NAn * 64 * 2);
    int2* payload_a = (int2*)alloc((size_t)NQn * SLOTS * 8);  // dst of E1/E2 < NQn
    int2* payload_q = (int2*)alloc((size_t)NQn * SLOTS * 8);
    char* zero_start = ws + off;
    int* cursor_a = (int*)alloc((size_t)NQn * 4);
    int* cursor_q = (int*)alloc((size_t)NQn * 4);
    char* zero_end = ws + off;
    u16* Wbig_q = (u16*)alloc(64 * 320 * 2);
    float* bbig_q = (float*)alloc(320 * 4);
    u16* Wbig_a = (u16*)alloc(64 * 192 * 2);
    float* bbig_a = (float*)alloc(192 * 4);

    if (off > ws_size) return;  // workspace too small: leave output zeroed (visible failure)

    hipMemsetAsync(zero_start, 0, (size_t)(zero_end - zero_start), stream);

    fold_kernel<<<64, 256, 0, stream>>>(Wk_qn, Wv_qn, Wq_qn, bk_qn, bv_qn, bq_qn,
                                        a_rel, m_rel, 0, 1, Wbig_q, bbig_q, 320);
    fold_kernel<<<64, 256, 0, stream>>>(Wk_an, Wv_an, Wq_an, bk_an, bv_an, bq_an,
                                        a_rel, m_rel, 2, -1, Wbig_a, bbig_a, 192);

    node_mfma<320><<<512, 256, 0, stream>>>(x_q, NQn, W_in_q, b_in_q, Wbig_q, bbig_q, h_q, big_q);
    node_mfma<192><<<768, 256, 0, stream>>>(x_a, NAn, W_in_a, b_in_a, Wbig_a, bbig_a, h_a, big_a);

    scatter_kernel<<<(E1n + 255) / 256, 256, 0, stream>>>(
        ei_qca, ei_qca + E1n, E1n, 320, 64, 0, w_qca, cursor_a, payload_a);
    scatter_kernel<<<(E2n + 255) / 256, 256, 0, stream>>>(
        ei_qwa, ei_qwa + E2n, E2n, 320, 192, 1, w_qwa, cursor_a, payload_a);
    scatter_kernel<<<(E3n + 255) / 256, 256, 0, stream>>>(
        ei_rev, ei_rev + E3n, E3n, 192, 64, 0, w_rev, cursor_q, payload_q);

    // answer-node aggregation: edges from q-nodes (big_q), q rows in big_a
    gather_finalize<<<3136, 256, 0, stream>>>(
        cursor_a, payload_a, big_q, big_a, 192, p_rel, 0, 1,
        h_a, Wo_an, bo_an, skip_an, z_a, NAn);
    // question-node aggregation: edges from a-nodes (big_a), q rows in big_q
    gather_finalize<<<1568, 256, 0, stream>>>(
        cursor_q, payload_q, big_a, big_q, 320, p_rel, 2, 2,
        h_q, Wo_qn, bo_qn, skip_qn, z_q, NQn);

    decoder_kernel<<<(2 * NLn * 32 + 255) / 256, 256, 0, stream>>>(
        z_q, z_a, pos_idx, neg_idx, (float*)d_out);
}